// Round 3
// baseline (791.285 us; speedup 1.0000x reference)
//
#include <hip/hip_runtime.h>
#include <stdint.h>

#define SS 768
#define CH 16
#define NCLS 5
#define BN_EPS 1e-4f
#define NBX 48                 // 768/16 : bucket grid (16x16 xy columns)
#define NB  (NBX * NBX)        // 2304 buckets

static constexpr size_t BM_WORDS = ((size_t)SS * SS * SS + 31) / 32;  // 14,155,776 u32
static constexpr size_t BM_BYTES = BM_WORDS * 4 + 64;                 // +slack for 64b windows

// ---------------- kernel 1: histogram points into 16x16 xy-column buckets ----------------
__global__ void hist_k(const float* __restrict__ pc, uint32_t* __restrict__ cnt, int n) {
    int i = blockIdx.x * blockDim.x + threadIdx.x;
    if (i >= n) return;
    int x = (int)pc[i * 5 + 0];
    int y = (int)pc[i * 5 + 1];
    atomicAdd(&cnt[(x >> 4) * NBX + (y >> 4)], 1u);
}

// ---------------- kernel 2: exclusive scan of 2304 counters (one wave) ----------------
__global__ void scan_k(uint32_t* __restrict__ cnt) {
    int lane = threadIdx.x;  // 64 threads, 1 block
    uint32_t carry = 0;
    for (int base = 0; base < NB; base += 64) {
        uint32_t v = cnt[base + lane];
        uint32_t s = v;
        for (int off = 1; off < 64; off <<= 1) {
            uint32_t u = __shfl_up(s, off, 64);
            if (lane >= off) s += u;
        }
        cnt[base + lane] = carry + s - v;        // exclusive prefix
        carry += __shfl(s, 63, 64);
    }
}

// ---------------- kernel 3: scatter packed records (key<<21 | idx) bucket-contiguously ----------------
__global__ void scatter_k(const float* __restrict__ pc, uint32_t* __restrict__ off,
                          unsigned long long* __restrict__ recs, int n) {
    int i = blockIdx.x * blockDim.x + threadIdx.x;
    if (i >= n) return;
    int x = (int)pc[i * 5 + 0];
    int y = (int)pc[i * 5 + 1];
    int z = (int)pc[i * 5 + 2];
    uint32_t key = ((uint32_t)x * SS + (uint32_t)y) * SS + (uint32_t)z;
    uint32_t pos = atomicAdd(&off[(x >> 4) * NBX + (y >> 4)], 1u);
    recs[pos] = ((unsigned long long)key << 21) | (uint32_t)i;
}

// ---------------- kernel 4: build flat bitmap from sorted records (clustered atomics) ----------------
__global__ void build_fine_k(const unsigned long long* __restrict__ recs,
                             uint32_t* __restrict__ bm, int n) {
    int i = blockIdx.x * blockDim.x + threadIdx.x;
    if (i >= n) return;
    uint32_t key = (uint32_t)(recs[i] >> 21);
    atomicOr(&bm[key >> 5], 1u << (key & 31));
}

// ---------------- kernel 5: 27-neighbor mask + BN stats over sorted records ----------------
__global__ void mask_stats_k(const unsigned long long* __restrict__ recs,
                             const uint32_t* __restrict__ bm, const float* __restrict__ W,
                             uint32_t* __restrict__ masks, float* __restrict__ sums, int n) {
    __shared__ float sW[27 * CH];
    __shared__ float sred[4][32];
    int t = threadIdx.x;
    for (int j = t; j < 27 * CH; j += blockDim.x) sW[j] = W[j];
    __syncthreads();

    int i = blockIdx.x * blockDim.x + t;
    float o[CH];
#pragma unroll
    for (int m = 0; m < CH; m++) o[m] = 0.f;

    if (i < n) {
        unsigned long long rec = recs[i];
        uint32_t key = (uint32_t)(rec >> 21);
        uint32_t idx = (uint32_t)(rec & 0x1FFFFFu);
        int z = (int)(key % SS);
        uint32_t t2 = key / SS;
        int y = (int)(t2 % SS);
        int x = (int)(t2 / SS);

        uint32_t mask = 0;
        int zlo = (z > 0) ? (z - 1) : 0;
#pragma unroll
        for (int dx = -1; dx <= 1; dx++) {
            int nx = x + dx;
            if ((unsigned)nx >= SS) continue;
#pragma unroll
            for (int dy = -1; dy <= 1; dy++) {
                int ny = y + dy;
                if ((unsigned)ny >= SS) continue;
                uint32_t base = ((uint32_t)nx * SS + (uint32_t)ny) * SS + (uint32_t)zlo;
                uint32_t wi = base >> 5, sh = base & 31;
                uint64_t dw = (uint64_t)bm[wi] | ((uint64_t)bm[wi + 1] << 32);
                uint32_t three = (uint32_t)(dw >> sh) & 7u;
                if (z == 0)      three = (three << 1) & 7u;  // dz=-1 invalid
                if (z == SS - 1) three &= 3u;                // dz=+1 wraps, invalid
                mask |= three << (((dx + 1) * 3 + (dy + 1)) * 3);
            }
        }
        masks[idx] = mask;
        uint32_t mm = mask;
        while (mm) {
            int k = __builtin_ctz(mm);
            mm &= mm - 1;
#pragma unroll
            for (int m = 0; m < CH; m++) o[m] += sW[k * CH + m];
        }
    }

    // wave butterfly reduce of sum & sumsq per channel, then one atomicAdd per block per slot
    int lane = t & 63, wid = t >> 6;
#pragma unroll
    for (int m = 0; m < CH; m++) {
        float v = o[m];
        float v2 = o[m] * o[m];
        for (int off = 32; off; off >>= 1) {
            v += __shfl_xor(v, off, 64);
            v2 += __shfl_xor(v2, off, 64);
        }
        if (lane == 0) { sred[wid][m] = v; sred[wid][16 + m] = v2; }
    }
    __syncthreads();
    if (t < 32) {
        float s = 0.f;
        int nw = blockDim.x >> 6;
        for (int w = 0; w < nw; w++) s += sred[w][t];
        atomicAdd(&sums[t], s);
    }
}

// ---------------- kernel 6: BN + ReLU + linear epilogue ----------------
__global__ void final_out(const uint32_t* __restrict__ masks, const float* __restrict__ W,
                          const float* __restrict__ sums, const float* __restrict__ gamma,
                          const float* __restrict__ beta, const float* __restrict__ lin_w,
                          const float* __restrict__ lin_b, float* __restrict__ out, int n) {
    __shared__ float sW[27 * CH];
    __shared__ float sA[CH], sB[CH], sLW[CH * NCLS], sLB[NCLS];
    int t = threadIdx.x;
    for (int j = t; j < 27 * CH; j += blockDim.x) sW[j] = W[j];
    if (t < CH) {
        float mean = sums[t] / (float)n;
        float var = sums[16 + t] / (float)n - mean * mean;
        float istd = rsqrtf(var + BN_EPS);
        float a = istd * gamma[t];
        sA[t] = a;
        sB[t] = beta[t] - mean * a;
    }
    if (t < CH * NCLS) sLW[t] = lin_w[t];
    if (t < NCLS) sLB[t] = lin_b[t];
    __syncthreads();

    int i = blockIdx.x * blockDim.x + t;
    if (i >= n) return;
    uint32_t mm = masks[i];
    float o[CH];
#pragma unroll
    for (int m = 0; m < CH; m++) o[m] = 0.f;
    while (mm) {
        int k = __builtin_ctz(mm);
        mm &= mm - 1;
#pragma unroll
        for (int m = 0; m < CH; m++) o[m] += sW[k * CH + m];
    }
    float res[NCLS];
#pragma unroll
    for (int c = 0; c < NCLS; c++) res[c] = sLB[c];
#pragma unroll
    for (int m = 0; m < CH; m++) {
        float h = fmaxf(o[m] * sA[m] + sB[m], 0.f);
#pragma unroll
        for (int c = 0; c < NCLS; c++) res[c] += h * sLW[m * NCLS + c];
    }
#pragma unroll
    for (int c = 0; c < NCLS; c++) out[(size_t)i * NCLS + c] = res[c];
}

extern "C" void kernel_launch(void* const* d_in, const int* in_sizes, int n_in,
                              void* d_out, int out_size, void* d_ws, size_t ws_size,
                              hipStream_t stream) {
    const float* pc    = (const float*)d_in[0];
    const float* W     = (const float*)d_in[1];
    const float* gamma = (const float*)d_in[2];
    const float* beta  = (const float*)d_in[3];
    const float* lin_w = (const float*)d_in[4];
    const float* lin_b = (const float*)d_in[5];
    float* out = (float*)d_out;

    int n = in_sizes[0] / 5;
    int nblk = (n + 255) / 256;

    // workspace layout: [sums 256B][bm 56.6MB][cnt 9216B][masks n*4]
    char* ws = (char*)d_ws;
    float* sums = (float*)ws;
    uint32_t* bm = (uint32_t*)(ws + 256);
    uint32_t* cnt = (uint32_t*)(ws + 256 + BM_BYTES);
    uint32_t* masks = (uint32_t*)(ws + 256 + BM_BYTES + NB * 4);
    size_t need = 256 + BM_BYTES + NB * 4 + (size_t)n * sizeof(uint32_t);
    if (ws_size < need) return;  // clean failure rather than OOB writes

    // records live in d_out scratch (n*8 = 16MB <= 40MB), dead before final_out writes it
    unsigned long long* recs = (unsigned long long*)d_out;

    hipMemsetAsync(ws, 0, 256 + BM_BYTES + NB * 4, stream);  // sums+bm+cnt contiguous
    hist_k<<<nblk, 256, 0, stream>>>(pc, cnt, n);
    scan_k<<<1, 64, 0, stream>>>(cnt);
    scatter_k<<<nblk, 256, 0, stream>>>(pc, cnt, recs, n);
    build_fine_k<<<nblk, 256, 0, stream>>>(recs, bm, n);
    mask_stats_k<<<nblk, 256, 0, stream>>>(recs, bm, W, masks, sums, n);
    final_out<<<nblk, 256, 0, stream>>>(masks, W, sums, gamma, beta, lin_w, lin_b, out, n);
}

// Round 5
// 266.938 us; speedup vs baseline: 2.9643x; 2.9643x over previous
//
#include <hip/hip_runtime.h>
#include <stdint.h>

#define SS 768
#define CH 16
#define NCLS 5
#define BN_EPS 1e-4f
#define NBX 48                 // 768/16 tiles per axis
#define NB  (NBX * NBX)        // 2304 tiles
#define G   256                // blocks for count/scatter passes
#define TW  18                 // tile width + 2 halo
#define ZW  25                 // u32 words per (lx,ly) z-column (770 bits used)

// ---------------- kernel 1: per-block privatized histogram (no global atomics) ----------------
__global__ void count_k(const float* __restrict__ pc, uint32_t* __restrict__ cnt, int n) {
    __shared__ uint32_t h[NB];
    int t = threadIdx.x, g = blockIdx.x;
    for (int j = t; j < NB; j += 256) h[j] = 0;
    __syncthreads();
    int chunk = (n + G - 1) / G;
    int lo = g * chunk, hi = min(n, lo + chunk);
    for (int i = lo + t; i < hi; i += 256) {
        int x = (int)pc[i * 5 + 0];
        int y = (int)pc[i * 5 + 1];
        atomicAdd(&h[(x >> 4) * NBX + (y >> 4)], 1u);
    }
    __syncthreads();
    for (int j = t; j < NB; j += 256) cnt[(size_t)j * G + g] = h[j];
}

// ---------------- kernel 2: per-bucket exclusive scan across blocks (in-place) ----------------
__global__ void scan1_k(uint32_t* __restrict__ cnt, uint32_t* __restrict__ tot) {
    int b = blockIdx.x, lane = threadIdx.x;   // 64 threads
    uint32_t* row = cnt + (size_t)b * G;
    uint32_t carry = 0;
    for (int c = 0; c < G; c += 64) {
        uint32_t v = row[c + lane];
        uint32_t s = v;
        for (int off = 1; off < 64; off <<= 1) {
            uint32_t u = __shfl_up(s, off, 64);
            if (lane >= off) s += u;
        }
        row[c + lane] = carry + s - v;
        carry += __shfl(s, 63, 64);
    }
    if (lane == 0) tot[b] = carry;
}

// ---------------- kernel 3: exclusive scan of bucket totals; zero sums ----------------
__global__ void scan2_k(const uint32_t* __restrict__ tot, uint32_t* __restrict__ base,
                        float* __restrict__ sums) {
    int lane = threadIdx.x;   // 64 threads, 1 block
    if (lane < 32) sums[lane] = 0.f;
    uint32_t carry = 0;
    for (int c = 0; c < NB; c += 64) {
        uint32_t v = tot[c + lane];
        uint32_t s = v;
        for (int off = 1; off < 64; off <<= 1) {
            uint32_t u = __shfl_up(s, off, 64);
            if (lane >= off) s += u;
        }
        base[c + lane] = carry + s - v;
        carry += __shfl(s, 63, 64);
    }
    if (lane == 0) base[NB] = carry;   // == n
}

// ---------------- kernel 4: scatter packed records (LDS rank replay, no global atomics) ----------------
__global__ void scatter2_k(const float* __restrict__ pc, const uint32_t* __restrict__ cnt,
                           const uint32_t* __restrict__ base, unsigned long long* __restrict__ recs,
                           int n) {
    __shared__ uint32_t pos[NB];
    int t = threadIdx.x, g = blockIdx.x;
    for (int j = t; j < NB; j += 256) pos[j] = base[j] + cnt[(size_t)j * G + g];
    __syncthreads();
    int chunk = (n + G - 1) / G;
    int lo = g * chunk, hi = min(n, lo + chunk);
    for (int i = lo + t; i < hi; i += 256) {
        int x = (int)pc[i * 5 + 0];
        int y = (int)pc[i * 5 + 1];
        int z = (int)pc[i * 5 + 2];
        int b = (x >> 4) * NBX + (y >> 4);
        uint32_t p = atomicAdd(&pos[b], 1u);
        recs[p] = ((unsigned long long)x << 41) | ((unsigned long long)y << 31) |
                  ((unsigned long long)z << 21) | (uint32_t)i;
    }
}

// ---------------- kernel 5: per-tile LDS bitmap + 27-neighbor masks + BN stats ----------------
__global__ void tile_k(const unsigned long long* __restrict__ recs, const uint32_t* __restrict__ base,
                       const float* __restrict__ W, uint32_t* __restrict__ masks_s,
                       float* __restrict__ sums) {
    __shared__ uint32_t lbm[TW * TW * ZW];   // 32,400 B
    __shared__ float sW[27 * CH];
    __shared__ float sred[4][32];
    int t = threadIdx.x;
    int b = blockIdx.x;
    int tx = b / NBX, ty = b % NBX;
    int x0 = tx * 16 - 1, y0 = ty * 16 - 1;

    for (int j = t; j < TW * TW * ZW; j += 256) lbm[j] = 0;
    for (int j = t; j < 27 * CH; j += 256) sW[j] = W[j];
    __syncthreads();

    // insert own + halo points into LDS bitmap (voxel z -> bit z+1 of its column)
    for (int dtx = -1; dtx <= 1; dtx++) {
        int ntx = tx + dtx;
        if ((unsigned)ntx >= NBX) continue;
        for (int dty = -1; dty <= 1; dty++) {
            int nty = ty + dty;
            if ((unsigned)nty >= NBX) continue;
            int nb = ntx * NBX + nty;
            uint32_t s0 = base[nb], s1 = base[nb + 1];
            for (uint32_t r = s0 + t; r < s1; r += 256) {
                unsigned long long rec = recs[r];
                int x = (int)(rec >> 41) & 1023;
                int y = (int)(rec >> 31) & 1023;
                int z = (int)(rec >> 21) & 1023;
                int lx = x - x0, ly = y - y0;
                if ((unsigned)lx < TW && (unsigned)ly < TW) {
                    int p = z + 1;
                    atomicOr(&lbm[(lx * TW + ly) * ZW + (p >> 5)], 1u << (p & 31));
                }
            }
        }
    }
    __syncthreads();

    float acc1[CH], acc2[CH];
#pragma unroll
    for (int m = 0; m < CH; m++) { acc1[m] = 0.f; acc2[m] = 0.f; }

    uint32_t s0 = base[b], s1 = base[b + 1];
    for (uint32_t i = s0 + t; i < s1; i += 256) {
        unsigned long long rec = recs[i];
        int x = (int)(rec >> 41) & 1023;
        int y = (int)(rec >> 31) & 1023;
        int z = (int)(rec >> 21) & 1023;
        uint32_t mask = 0;
#pragma unroll
        for (int dx = -1; dx <= 1; dx++) {
            int nx = x + dx;
            if ((unsigned)nx >= SS) continue;
            int lx = nx - x0;
#pragma unroll
            for (int dy = -1; dy <= 1; dy++) {
                int ny = y + dy;
                if ((unsigned)ny >= SS) continue;
                int ly = ny - y0;
                const uint32_t* col = &lbm[(lx * TW + ly) * ZW];
                uint32_t w = (uint32_t)z >> 5, sh = (uint32_t)z & 31;
                uint64_t dw = (uint64_t)col[w] | ((uint64_t)col[w + 1] << 32);
                uint32_t three = (uint32_t)((dw >> sh) & 7ull);  // bits z..z+2 = dz -1,0,+1
                mask |= three << (((dx + 1) * 3 + (dy + 1)) * 3);
            }
        }
        masks_s[i] = mask;

        // per-POINT output, then accumulate sum and sum-of-squares separately
        float o[CH];
#pragma unroll
        for (int m = 0; m < CH; m++) o[m] = 0.f;
        uint32_t mm = mask;
        while (mm) {
            int k = __builtin_ctz(mm);
            mm &= mm - 1;
#pragma unroll
            for (int m = 0; m < CH; m++) o[m] += sW[k * CH + m];
        }
#pragma unroll
        for (int m = 0; m < CH; m++) { acc1[m] += o[m]; acc2[m] += o[m] * o[m]; }
    }

    // block-reduce sum & sumsq, one atomicAdd per slot per block
    int lane = t & 63, wid = t >> 6;
#pragma unroll
    for (int m = 0; m < CH; m++) {
        float v = acc1[m];
        float v2 = acc2[m];
        for (int off = 32; off; off >>= 1) {
            v += __shfl_xor(v, off, 64);
            v2 += __shfl_xor(v2, off, 64);
        }
        if (lane == 0) { sred[wid][m] = v; sred[wid][16 + m] = v2; }
    }
    __syncthreads();
    if (t < 32) {
        float s = 0.f;
        for (int w = 0; w < 4; w++) s += sred[w][t];
        atomicAdd(&sums[t], s);
    }
}

// ---------------- kernel 6: BN + ReLU + linear epilogue (scatter to original order) ----------------
__global__ void final2_k(const unsigned long long* __restrict__ recs,
                         const uint32_t* __restrict__ masks_s, const float* __restrict__ W,
                         const float* __restrict__ sums, const float* __restrict__ gamma,
                         const float* __restrict__ beta, const float* __restrict__ lin_w,
                         const float* __restrict__ lin_b, float* __restrict__ out, int n) {
    __shared__ float sW[27 * CH];
    __shared__ float sA[CH], sB[CH], sLW[CH * NCLS], sLB[NCLS];
    int t = threadIdx.x;
    for (int j = t; j < 27 * CH; j += blockDim.x) sW[j] = W[j];
    if (t < CH) {
        float mean = sums[t] / (float)n;
        float var = sums[16 + t] / (float)n - mean * mean;
        float istd = rsqrtf(var + BN_EPS);
        float a = istd * gamma[t];
        sA[t] = a;
        sB[t] = beta[t] - mean * a;
    }
    if (t < CH * NCLS) sLW[t] = lin_w[t];
    if (t < NCLS) sLB[t] = lin_b[t];
    __syncthreads();

    int i = blockIdx.x * blockDim.x + t;
    if (i >= n) return;
    uint32_t idx = (uint32_t)(recs[i] & 0x1FFFFFu);
    uint32_t mm = masks_s[i];
    float o[CH];
#pragma unroll
    for (int m = 0; m < CH; m++) o[m] = 0.f;
    while (mm) {
        int k = __builtin_ctz(mm);
        mm &= mm - 1;
#pragma unroll
        for (int m = 0; m < CH; m++) o[m] += sW[k * CH + m];
    }
    float res[NCLS];
#pragma unroll
    for (int c = 0; c < NCLS; c++) res[c] = sLB[c];
#pragma unroll
    for (int m = 0; m < CH; m++) {
        float h = fmaxf(o[m] * sA[m] + sB[m], 0.f);
#pragma unroll
        for (int c = 0; c < NCLS; c++) res[c] += h * sLW[m * NCLS + c];
    }
#pragma unroll
    for (int c = 0; c < NCLS; c++) out[(size_t)idx * NCLS + c] = res[c];
}

extern "C" void kernel_launch(void* const* d_in, const int* in_sizes, int n_in,
                              void* d_out, int out_size, void* d_ws, size_t ws_size,
                              hipStream_t stream) {
    const float* pc    = (const float*)d_in[0];
    const float* W     = (const float*)d_in[1];
    const float* gamma = (const float*)d_in[2];
    const float* beta  = (const float*)d_in[3];
    const float* lin_w = (const float*)d_in[4];
    const float* lin_b = (const float*)d_in[5];
    float* out = (float*)d_out;

    int n = in_sizes[0] / 5;
    int nblk = (n + 255) / 256;

    // workspace: [sums 256B][cnt NB*G*4][tot NB*4][base (NB+1)*4][recs n*8][masks n*4]  ~26.4MB
    char* ws = (char*)d_ws;
    float* sums = (float*)ws;
    uint32_t* cnt = (uint32_t*)(ws + 256);
    size_t off = 256 + (size_t)NB * G * 4;
    uint32_t* tot = (uint32_t*)(ws + off);   off += (size_t)NB * 4;
    uint32_t* base = (uint32_t*)(ws + off);  off += (size_t)(NB + 1) * 4;
    off = (off + 255) & ~(size_t)255;
    unsigned long long* recs = (unsigned long long*)(ws + off);  off += (size_t)n * 8;
    uint32_t* masks_s = (uint32_t*)(ws + off);                   off += (size_t)n * 4;
    if (ws_size < off) return;  // clean failure rather than OOB writes

    count_k  <<<G, 256, 0, stream>>>(pc, cnt, n);
    scan1_k  <<<NB, 64, 0, stream>>>(cnt, tot);
    scan2_k  <<<1, 64, 0, stream>>>(tot, base, sums);
    scatter2_k<<<G, 256, 0, stream>>>(pc, cnt, base, recs, n);
    tile_k   <<<NB, 256, 0, stream>>>(recs, base, W, masks_s, sums);
    final2_k <<<nblk, 256, 0, stream>>>(recs, masks_s, W, sums, gamma, beta, lin_w, lin_b, out, n);
}

// Round 6
// 248.515 us; speedup vs baseline: 3.1841x; 1.0741x over previous
//
#include <hip/hip_runtime.h>
#include <stdint.h>

#define SS 768
#define CH 16
#define NCLS 5
#define BN_EPS 1e-4f
#define NBX 48                 // 768/16 tiles per axis
#define NB  (NBX * NBX)        // 2304 tiles
#define G   256                // blocks for count/scatter passes
#define TW  18                 // tile width + 2 halo
#define ZW  25                 // u32 words per (lx,ly) z-column (770 bits used)
#define CBS 257                // cellbase row stride (256 cells + total)

// ---------------- kernel 1: per-block privatized histogram (no global atomics) ----------------
__global__ void count_k(const float* __restrict__ pc, uint32_t* __restrict__ cnt, int n) {
    __shared__ uint32_t h[NB];
    int t = threadIdx.x, g = blockIdx.x;
    for (int j = t; j < NB; j += 256) h[j] = 0;
    __syncthreads();
    int chunk = (n + G - 1) / G;
    int lo = g * chunk, hi = min(n, lo + chunk);
    for (int i = lo + t; i < hi; i += 256) {
        int x = (int)pc[i * 5 + 0];
        int y = (int)pc[i * 5 + 1];
        atomicAdd(&h[(x >> 4) * NBX + (y >> 4)], 1u);
    }
    __syncthreads();
    for (int j = t; j < NB; j += 256) cnt[(size_t)j * G + g] = h[j];
}

// ---------------- kernel 2: per-bucket exclusive scan across blocks (in-place) ----------------
__global__ void scan1_k(uint32_t* __restrict__ cnt, uint32_t* __restrict__ tot) {
    int b = blockIdx.x, lane = threadIdx.x;   // 64 threads
    uint32_t* row = cnt + (size_t)b * G;
    uint32_t carry = 0;
    for (int c = 0; c < G; c += 64) {
        uint32_t v = row[c + lane];
        uint32_t s = v;
        for (int off = 1; off < 64; off <<= 1) {
            uint32_t u = __shfl_up(s, off, 64);
            if (lane >= off) s += u;
        }
        row[c + lane] = carry + s - v;
        carry += __shfl(s, 63, 64);
    }
    if (lane == 0) tot[b] = carry;
}

// ---------------- kernel 3: exclusive scan of bucket totals; zero sums ----------------
__global__ void scan2_k(const uint32_t* __restrict__ tot, uint32_t* __restrict__ base,
                        float* __restrict__ sums) {
    int lane = threadIdx.x;   // 64 threads, 1 block
    if (lane < 32) sums[lane] = 0.f;
    uint32_t carry = 0;
    for (int c = 0; c < NB; c += 64) {
        uint32_t v = tot[c + lane];
        uint32_t s = v;
        for (int off = 1; off < 64; off <<= 1) {
            uint32_t u = __shfl_up(s, off, 64);
            if (lane >= off) s += u;
        }
        base[c + lane] = carry + s - v;
        carry += __shfl(s, 63, 64);
    }
    if (lane == 0) base[NB] = carry;   // == n
}

// ---------------- kernel 4: scatter packed records (LDS rank replay, no global atomics) ----------------
__global__ void scatter2_k(const float* __restrict__ pc, const uint32_t* __restrict__ cnt,
                           const uint32_t* __restrict__ base, unsigned long long* __restrict__ recs,
                           int n) {
    __shared__ uint32_t pos[NB];
    int t = threadIdx.x, g = blockIdx.x;
    for (int j = t; j < NB; j += 256) pos[j] = base[j] + cnt[(size_t)j * G + g];
    __syncthreads();
    int chunk = (n + G - 1) / G;
    int lo = g * chunk, hi = min(n, lo + chunk);
    for (int i = lo + t; i < hi; i += 256) {
        int x = (int)pc[i * 5 + 0];
        int y = (int)pc[i * 5 + 1];
        int z = (int)pc[i * 5 + 2];
        int b = (x >> 4) * NBX + (y >> 4);
        uint32_t p = atomicAdd(&pos[b], 1u);
        recs[p] = ((unsigned long long)x << 41) | ((unsigned long long)y << 31) |
                  ((unsigned long long)z << 21) | (uint32_t)i;
    }
}

// ---------------- kernel 5: per-bucket cell sort (LDS hist+scan, contention-free) ----------------
__global__ void sortcells_k(const unsigned long long* __restrict__ recs,
                            const uint32_t* __restrict__ base,
                            unsigned long long* __restrict__ recs2,
                            uint32_t* __restrict__ cellbase) {
    __shared__ uint32_t h[256], pos2[256], wt[4], wo[4];
    int t = threadIdx.x, b = blockIdx.x;
    uint32_t s0 = base[b], s1 = base[b + 1];
    h[t] = 0;
    __syncthreads();
    for (uint32_t r = s0 + t; r < s1; r += 256) {
        unsigned long long rec = recs[r];
        int x = (int)(rec >> 41) & 1023, y = (int)(rec >> 31) & 1023;
        atomicAdd(&h[(x & 15) * 16 + (y & 15)], 1u);
    }
    __syncthreads();
    int lane = t & 63, wid = t >> 6;
    uint32_t v = h[t], s = v;
    for (int off = 1; off < 64; off <<= 1) {
        uint32_t u = __shfl_up(s, off, 64);
        if (lane >= off) s += u;
    }
    if (lane == 63) wt[wid] = s;
    __syncthreads();
    if (t == 0) { uint32_t c = 0; for (int w = 0; w < 4; w++) { uint32_t x = wt[w]; wo[w] = c; c += x; } }
    __syncthreads();
    uint32_t excl = s - v + wo[wid];
    cellbase[(size_t)b * CBS + t] = excl;
    if (t == 255) cellbase[(size_t)b * CBS + 256] = excl + v;
    pos2[t] = excl;
    __syncthreads();
    for (uint32_t r = s0 + t; r < s1; r += 256) {
        unsigned long long rec = recs[r];
        int x = (int)(rec >> 41) & 1023, y = (int)(rec >> 31) & 1023;
        uint32_t p = atomicAdd(&pos2[(x & 15) * 16 + (y & 15)], 1u);
        recs2[s0 + p] = rec;
    }
}

// ---------------- kernel 6: per-tile LDS bitmap, exact halo ranges, branchless probe ----------------
__global__ void tile_k(const unsigned long long* __restrict__ recs2,
                       const uint32_t* __restrict__ base, const uint32_t* __restrict__ cellbase,
                       const float* __restrict__ W, uint32_t* __restrict__ masks,
                       float* __restrict__ sums) {
    __shared__ uint32_t lbm[TW * TW * ZW];   // 32,400 B
    __shared__ float sW[27 * CH];
    __shared__ float sred[4][32];
    __shared__ uint32_t sbeg[40], soff[40];
    int t = threadIdx.x;
    int b = blockIdx.x;
    int tx = b / NBX, ty = b % NBX;
    int x0 = tx * 16 - 1, y0 = ty * 16 - 1;

    unsigned long long* lb8 = (unsigned long long*)lbm;
    for (int j = t; j < TW * TW * ZW / 2; j += 256) lb8[j] = 0ull;
    for (int j = t; j < 27 * CH; j += 256) sW[j] = W[j];

    // 39 exact halo segments: (bucket, cell-range) -> global record range
    if (t < 39) {
        int nb = -1, c0 = 0, c1 = 0;
        if (t == 0)      { nb = b; c0 = 0; c1 = 256; }
        else if (t == 1) { if (tx + 1 < NBX) nb = (tx + 1) * NBX + ty; c0 = 0;   c1 = 16;  }
        else if (t == 2) { if (tx > 0)       nb = (tx - 1) * NBX + ty; c0 = 240; c1 = 256; }
        else if (t < 19) { int lx = t - 3;  if (ty > 0)       nb = tx * NBX + (ty - 1); c0 = lx * 16 + 15; c1 = c0 + 1; }
        else if (t < 35) { int lx = t - 19; if (ty + 1 < NBX) nb = tx * NBX + (ty + 1); c0 = lx * 16;      c1 = c0 + 1; }
        else if (t == 35) { if (tx + 1 < NBX && ty > 0)       nb = (tx + 1) * NBX + (ty - 1); c0 = 15;  c1 = 16;  }
        else if (t == 36) { if (tx + 1 < NBX && ty + 1 < NBX) nb = (tx + 1) * NBX + (ty + 1); c0 = 0;   c1 = 1;   }
        else if (t == 37) { if (tx > 0 && ty > 0)             nb = (tx - 1) * NBX + (ty - 1); c0 = 255; c1 = 256; }
        else              { if (tx > 0 && ty + 1 < NBX)       nb = (tx - 1) * NBX + (ty + 1); c0 = 240; c1 = 241; }
        uint32_t g0 = 0, len = 0;
        if (nb >= 0) {
            uint32_t bb = base[nb];
            uint32_t cb0 = cellbase[(size_t)nb * CBS + c0];
            uint32_t cb1 = cellbase[(size_t)nb * CBS + c1];
            g0 = bb + cb0; len = cb1 - cb0;
        }
        sbeg[t] = g0; soff[t] = len;
    }
    __syncthreads();
    if (t == 0) {
        uint32_t c = 0;
        for (int i = 0; i < 39; i++) { uint32_t l = soff[i]; soff[i] = c; c += l; }
        soff[39] = c;
    }
    __syncthreads();
    uint32_t T = soff[39];
    for (uint32_t w = t; w < T; w += 256) {
        int lo = 0, hi = 38;
        while (lo < hi) { int mid = (lo + hi + 1) >> 1; if (soff[mid] <= w) lo = mid; else hi = mid - 1; }
        uint32_t gr = sbeg[lo] + (w - soff[lo]);
        unsigned long long rec = recs2[gr];
        int x = (int)(rec >> 41) & 1023;
        int y = (int)(rec >> 31) & 1023;
        int z = (int)(rec >> 21) & 1023;
        int p = z + 1;
        atomicOr(&lbm[((x - x0) * TW + (y - y0)) * ZW + (p >> 5)], 1u << (p & 31));
    }
    __syncthreads();

    float acc1[CH], acc2[CH];
#pragma unroll
    for (int m = 0; m < CH; m++) { acc1[m] = 0.f; acc2[m] = 0.f; }

    uint32_t s0 = base[b], s1 = base[b + 1];
    for (uint32_t i = s0 + t; i < s1; i += 256) {
        unsigned long long rec = recs2[i];
        int x = (int)(rec >> 41) & 1023;
        int y = (int)(rec >> 31) & 1023;
        int z = (int)(rec >> 21) & 1023;
        uint32_t idx = (uint32_t)(rec & 0x1FFFFFu);
        int bc = ((x - x0) * TW + (y - y0)) * ZW + (z >> 5);
        uint32_t sh = (uint32_t)z & 31;
        uint32_t mask = 0;
#pragma unroll
        for (int dx = -1; dx <= 1; dx++) {
#pragma unroll
            for (int dy = -1; dy <= 1; dy++) {
                int c = bc + (dx * TW + dy) * ZW;
                uint64_t dw = (uint64_t)lbm[c] | ((uint64_t)lbm[c + 1] << 32);
                mask |= ((uint32_t)(dw >> sh) & 7u) << (((dx + 1) * 3 + (dy + 1)) * 3);
            }
        }
        masks[idx] = mask;

        float o[CH];
#pragma unroll
        for (int m = 0; m < CH; m++) o[m] = 0.f;
        uint32_t mm = mask;
        while (mm) {
            int k = __builtin_ctz(mm);
            mm &= mm - 1;
#pragma unroll
            for (int m = 0; m < CH; m++) o[m] += sW[k * CH + m];
        }
#pragma unroll
        for (int m = 0; m < CH; m++) { acc1[m] += o[m]; acc2[m] += o[m] * o[m]; }
    }

    int lane = t & 63, wid = t >> 6;
#pragma unroll
    for (int m = 0; m < CH; m++) {
        float v = acc1[m];
        float v2 = acc2[m];
        for (int off = 32; off; off >>= 1) {
            v += __shfl_xor(v, off, 64);
            v2 += __shfl_xor(v2, off, 64);
        }
        if (lane == 0) { sred[wid][m] = v; sred[wid][16 + m] = v2; }
    }
    __syncthreads();
    if (t < 32) {
        float s = 0.f;
        for (int w = 0; w < 4; w++) s += sred[w][t];
        atomicAdd(&sums[t], s);
    }
}

// ---------------- kernel 7: fully-coalesced BN + ReLU + linear epilogue ----------------
__global__ void final3_k(const uint32_t* __restrict__ masks, const float* __restrict__ W,
                         const float* __restrict__ sums, const float* __restrict__ gamma,
                         const float* __restrict__ beta, const float* __restrict__ lin_w,
                         const float* __restrict__ lin_b, float* __restrict__ out, int n) {
    __shared__ float sW[27 * CH];
    __shared__ float sA[CH], sB[CH], sLW[CH * NCLS], sLB[NCLS];
    int t = threadIdx.x;
    for (int j = t; j < 27 * CH; j += blockDim.x) sW[j] = W[j];
    if (t < CH) {
        float mean = sums[t] / (float)n;
        float var = sums[16 + t] / (float)n - mean * mean;
        float istd = rsqrtf(var + BN_EPS);
        float a = istd * gamma[t];
        sA[t] = a;
        sB[t] = beta[t] - mean * a;
    }
    if (t < CH * NCLS) sLW[t] = lin_w[t];
    if (t < NCLS) sLB[t] = lin_b[t];
    __syncthreads();

    int i = blockIdx.x * blockDim.x + t;
    if (i >= n) return;
    uint32_t mm = masks[i];
    float o[CH];
#pragma unroll
    for (int m = 0; m < CH; m++) o[m] = 0.f;
    while (mm) {
        int k = __builtin_ctz(mm);
        mm &= mm - 1;
#pragma unroll
        for (int m = 0; m < CH; m++) o[m] += sW[k * CH + m];
    }
    float res[NCLS];
#pragma unroll
    for (int c = 0; c < NCLS; c++) res[c] = sLB[c];
#pragma unroll
    for (int m = 0; m < CH; m++) {
        float h = fmaxf(o[m] * sA[m] + sB[m], 0.f);
#pragma unroll
        for (int c = 0; c < NCLS; c++) res[c] += h * sLW[m * NCLS + c];
    }
#pragma unroll
    for (int c = 0; c < NCLS; c++) out[(size_t)i * NCLS + c] = res[c];
}

extern "C" void kernel_launch(void* const* d_in, const int* in_sizes, int n_in,
                              void* d_out, int out_size, void* d_ws, size_t ws_size,
                              hipStream_t stream) {
    const float* pc    = (const float*)d_in[0];
    const float* W     = (const float*)d_in[1];
    const float* gamma = (const float*)d_in[2];
    const float* beta  = (const float*)d_in[3];
    const float* lin_w = (const float*)d_in[4];
    const float* lin_b = (const float*)d_in[5];
    float* out = (float*)d_out;

    int n = in_sizes[0] / 5;
    int nblk = (n + 255) / 256;

    // workspace: [sums][cnt NB*G][tot NB][base NB+1][recs n*8][recs2 n*8][cellbase NB*257][masks n*4]
    char* ws = (char*)d_ws;
    float* sums = (float*)ws;
    uint32_t* cnt = (uint32_t*)(ws + 256);
    size_t off = 256 + (size_t)NB * G * 4;
    uint32_t* tot = (uint32_t*)(ws + off);   off += (size_t)NB * 4;
    uint32_t* base = (uint32_t*)(ws + off);  off += (size_t)(NB + 1) * 4;
    off = (off + 255) & ~(size_t)255;
    unsigned long long* recs  = (unsigned long long*)(ws + off); off += (size_t)n * 8;
    unsigned long long* recs2 = (unsigned long long*)(ws + off); off += (size_t)n * 8;
    uint32_t* cellbase = (uint32_t*)(ws + off); off += (size_t)NB * CBS * 4;
    off = (off + 255) & ~(size_t)255;
    uint32_t* masks = (uint32_t*)(ws + off); off += (size_t)n * 4;
    if (ws_size < off) return;  // clean failure rather than OOB writes

    count_k   <<<G, 256, 0, stream>>>(pc, cnt, n);
    scan1_k   <<<NB, 64, 0, stream>>>(cnt, tot);
    scan2_k   <<<1, 64, 0, stream>>>(tot, base, sums);
    scatter2_k<<<G, 256, 0, stream>>>(pc, cnt, base, recs, n);
    sortcells_k<<<NB, 256, 0, stream>>>(recs, base, recs2, cellbase);
    tile_k    <<<NB, 256, 0, stream>>>(recs2, base, cellbase, W, masks, sums);
    final3_k  <<<nblk, 256, 0, stream>>>(masks, W, sums, gamma, beta, lin_w, lin_b, out, n);
}